// Round 10
// baseline (344.706 us; speedup 1.0000x reference)
//
#include <hip/hip_runtime.h>
#include <hip/hip_bf16.h>

#define N_NODES 50000
#define N_EDGES 400000
#define IN_DIM 24
#define HID 256
#define OUT_DIM 12

typedef _Float16 fp16_t;
typedef __attribute__((ext_vector_type(8))) _Float16 half8;
typedef __attribute__((ext_vector_type(4))) float f32x4;

// async global->LDS, 16 bytes per lane (dest must be linear: base + lane*16 per wave)
__device__ __forceinline__ void gload_lds16(const void* g, void* l) {
    typedef __attribute__((address_space(3))) unsigned int u32_lds;
    typedef const __attribute__((address_space(1))) unsigned int u32_glb;
    __builtin_amdgcn_global_load_lds((u32_glb*)(unsigned long long)g,
                                     (u32_lds*)(unsigned int)(unsigned long long)l,
                                     16, 0, 0);
}

// ---------------- encoder layer 1 (K=24, f32 compute, fp16 out) ----------------
template<int K, int M, int ROWS>
__global__ __launch_bounds__(M) void lin_enc1(const float* __restrict__ X,
                                              const float* __restrict__ W,
                                              const float* __restrict__ b,
                                              fp16_t* __restrict__ Y, int N) {
    __shared__ float xs[ROWS][K];
    const int row0 = blockIdx.x * ROWS;
    const int tid = threadIdx.x;
    for (int i = tid; i < ROWS * K; i += M) {
        int r = i / K, k = i - r * K;
        int gr = row0 + r;
        xs[r][k] = (gr < N) ? X[(long long)gr * K + k] : 0.f;
    }
    __syncthreads();
    const int j = tid;
    float acc[ROWS];
    float bj = b[j];
#pragma unroll
    for (int r = 0; r < ROWS; ++r) acc[r] = bj;
    for (int k = 0; k < K; ++k) {
        float w = W[k * M + j];
#pragma unroll
        for (int r = 0; r < ROWS; ++r) acc[r] = fmaf(xs[r][k], w, acc[r]);
    }
#pragma unroll
    for (int r = 0; r < ROWS; ++r) {
        int gr = row0 + r;
        if (gr < N) {
            float v = fmaxf(acc[r], 0.f);
            Y[(size_t)gr * M + j] = (fp16_t)v;
        }
    }
}

// ---------------- fused weight transpose + fp16 hi/lo split (all 4 weight sets) ----------------
__global__ __launch_bounds__(256) void wtrans_all(
    const float* __restrict__ enc_w2,
    const float* __restrict__ s1_wl, const float* __restrict__ s1_wr,
    const float* __restrict__ s2_wl, const float* __restrict__ s2_wr,
    const float* __restrict__ ro_w1,
    fp16_t* __restrict__ wtE_hi, fp16_t* __restrict__ wtE_lo,
    fp16_t* __restrict__ wtS1_hi, fp16_t* __restrict__ wtS1_lo,
    fp16_t* __restrict__ wtS2_hi, fp16_t* __restrict__ wtS2_lo,
    fp16_t* __restrict__ wtR_hi, fp16_t* __restrict__ wtR_lo) {
    const int sE = 256 * 128, sS = 256 * 512, sR = 128 * 256;
    int idx = blockIdx.x * blockDim.x + threadIdx.x;
    float v; fp16_t *ph, *pl; int o;
    if (idx < sE) {
        int j = idx / 128, k = idx - j * 128;
        v = enc_w2[(size_t)k * 256 + j]; ph = wtE_hi; pl = wtE_lo; o = idx;
    } else if (idx < sE + sS) {
        int t = idx - sE; int j = t / 512, k = t - j * 512;
        v = (k < 256) ? s1_wl[(size_t)k * 256 + j] : s1_wr[(size_t)(k - 256) * 256 + j];
        ph = wtS1_hi; pl = wtS1_lo; o = t;
    } else if (idx < sE + 2 * sS) {
        int t = idx - sE - sS; int j = t / 512, k = t - j * 512;
        v = (k < 256) ? s2_wl[(size_t)k * 256 + j] : s2_wr[(size_t)(k - 256) * 256 + j];
        ph = wtS2_hi; pl = wtS2_lo; o = t;
    } else if (idx < sE + 2 * sS + sR) {
        int t = idx - sE - 2 * sS; int j = t / 256, k = t - j * 256;
        v = ro_w1[(size_t)k * 128 + j]; ph = wtR_hi; pl = wtR_lo; o = t;
    } else return;
    fp16_t h = (fp16_t)v;
    ph[o] = h;
    pl[o] = (fp16_t)(v - (float)h);
}

// ---------------- MFMA fp16 GEMM: Y = relu?(A @ (Whi+Wlo)^T + b) ----------------
// Block tile BM x BN, BK=32. Waves (BM/64)x(BN/64), wave tile 64x64 (4x4 frags 16x16x32).
// LDS chunks XOR-swizzled (chunk col g ^ (row&3)) via pre-swizzled global source so
// frag ds_read_b128 spreads each half-wave across all 32 banks.
// MODE 0: A rows from A [N][K];  MODE 1: k<HID from A (mean), else A2 (h), both [N][HID]
template<int K, int MODE, int BM, int BN, bool WF32, bool WH16, bool RELU>
__global__ __launch_bounds__((BM / 64) * (BN / 64) * 64, 3) void gemm_mfma(
    const fp16_t* __restrict__ A, const fp16_t* __restrict__ A2,
    const fp16_t* __restrict__ Whi, const fp16_t* __restrict__ Wlo,
    const float* __restrict__ bias,
    float* __restrict__ Yf, fp16_t* __restrict__ Yh,
    int N, int M) {
    constexpr int NWR = BM / 64;
    constexpr int NWC = BN / 64;
    constexpr int NT = NWR * NWC * 64;
    __shared__ __align__(16) fp16_t ldsA[BM * 32];
    __shared__ __align__(16) fp16_t ldsBh[BN * 32];
    __shared__ __align__(16) fp16_t ldsBl[BN * 32];
    const int tid = threadIdx.x;
    const int r0 = blockIdx.x * BM;
    const int j0 = blockIdx.y * BN;
    const int w = tid >> 6, lane = tid & 63;
    const int wr = w / NWC, wc = w % NWC;
    const int lrow = lane & 15, lg = lane >> 4;
    const int swlg = lg ^ (lrow & 3);   // swizzled chunk column for frag reads

    f32x4 acc[4][4] = {};

    for (int kc = 0; kc < K; kc += 32) {
        __syncthreads();
        // ---- stage A tile (BM x 32): BM*4 16B chunks, source column pre-swizzled ----
        const fp16_t* pa;
        int ka, KA;
        if (MODE == 1) {
            KA = HID;
            if (kc >= HID) { pa = A2; ka = kc - HID; }
            else           { pa = A;  ka = kc; }
        } else {
            KA = K; pa = A; ka = kc;
        }
#pragma unroll
        for (int c = tid; c < BM * 4; c += NT) {
            int row = c >> 2, g = c & 3;
            int gsw = g ^ (row & 3);
            int gr = r0 + row; if (gr > N - 1) gr = N - 1;
            size_t go = (size_t)gr * KA + ka + gsw * 8;
            gload_lds16(pa + go, (char*)ldsA + (size_t)c * 16);
        }
        // ---- stage B tiles (BN x 32, hi+lo) ----
#pragma unroll
        for (int c = tid; c < BN * 4; c += NT) {
            int row = c >> 2, g = c & 3;
            int gsw = g ^ (row & 3);
            size_t go = (size_t)(j0 + row) * K + kc + gsw * 8;
            gload_lds16(Whi + go, (char*)ldsBh + (size_t)c * 16);
            gload_lds16(Wlo + go, (char*)ldsBl + (size_t)c * 16);
        }
        __syncthreads();

        half8 a[4], bh[4], bl[4];
#pragma unroll
        for (int f = 0; f < 4; ++f) {
            int ar = wr * 64 + f * 16 + lrow;
            a[f] = *(const half8*)&ldsA[ar * 32 + swlg * 8];
            int br = wc * 64 + f * 16 + lrow;
            bh[f] = *(const half8*)&ldsBh[br * 32 + swlg * 8];
            bl[f] = *(const half8*)&ldsBl[br * 32 + swlg * 8];
        }
#pragma unroll
        for (int fi = 0; fi < 4; ++fi)
#pragma unroll
            for (int fj = 0; fj < 4; ++fj) {
                acc[fi][fj] = __builtin_amdgcn_mfma_f32_16x16x32_f16(a[fi], bh[fj], acc[fi][fj], 0, 0, 0);
                acc[fi][fj] = __builtin_amdgcn_mfma_f32_16x16x32_f16(a[fi], bl[fj], acc[fi][fj], 0, 0, 0);
            }
    }

    // ---- epilogue: C/D layout col=lane&15, row=(lane>>4)*4+reg ----
#pragma unroll
    for (int fj = 0; fj < 4; ++fj) {
        int ocol = j0 + wc * 64 + fj * 16 + lrow;
        float bv = bias[ocol];
#pragma unroll
        for (int fi = 0; fi < 4; ++fi) {
#pragma unroll
            for (int r = 0; r < 4; ++r) {
                int orow = r0 + wr * 64 + fi * 16 + lg * 4 + r;
                if (orow < N) {
                    float v = acc[fi][fj][r] + bv;
                    if (RELU) v = fmaxf(v, 0.f);
                    size_t o = (size_t)orow * M + ocol;
                    if (WF32) Yf[o] = v;
                    if (WH16) Yh[o] = (fp16_t)v;
                }
            }
        }
    }
}

// ---------------- CSR build ----------------
__global__ __launch_bounds__(1024) void zero_kernel(int* __restrict__ p, int n) {
    int i = blockIdx.x * blockDim.x + threadIdx.x;
    if (i < n) p[i] = 0;
}

__global__ void deg_kernel(const int* __restrict__ dst, int* __restrict__ deg, int E) {
    int e = blockIdx.x * blockDim.x + threadIdx.x;
    if (e < E) atomicAdd(&deg[dst[e]], 1);
}

// Stage 1: per-block inclusive scan (256 elems/block) + block total
__global__ __launch_bounds__(256) void scan_local(const int* __restrict__ deg,
                                                  int* __restrict__ locincl,
                                                  int* __restrict__ bsum, int N) {
    const int t = threadIdx.x;
    const int i = blockIdx.x * 256 + t;
    int v = (i < N) ? deg[i] : 0;
    const int lane = t & 63;
    int x = v;
#pragma unroll
    for (int off = 1; off < 64; off <<= 1) {
        int y = __shfl_up(x, off, 64);
        if (lane >= off) x += y;
    }
    __shared__ int wsum[4];
    if (lane == 63) wsum[t >> 6] = x;
    __syncthreads();
    const int wid = t >> 6;
    int add = 0;
    for (int wI = 0; wI < wid; ++wI) add += wsum[wI];
    x += add;
    if (i < N) locincl[i] = x;
    if (t == 255) bsum[blockIdx.x] = x;
}

// Stage 2: exclusive scan of block sums (B <= 256), single block
__global__ __launch_bounds__(256) void scan_bsum(int* __restrict__ bsum, int B) {
    const int t = threadIdx.x;
    int v = (t < B) ? bsum[t] : 0;
    const int lane = t & 63;
    int x = v;
#pragma unroll
    for (int off = 1; off < 64; off <<= 1) {
        int y = __shfl_up(x, off, 64);
        if (lane >= off) x += y;
    }
    __shared__ int wsum[4];
    if (lane == 63) wsum[t >> 6] = x;
    __syncthreads();
    const int wid = t >> 6;
    int add = 0;
    for (int wI = 0; wI < wid; ++wI) add += wsum[wI];
    x += add;
    if (t < B) bsum[t] = x - v;   // exclusive
}

// Stage 3: recombine -> exclusive rowptr + cursor
__global__ __launch_bounds__(256) void scan_final(const int* __restrict__ deg,
                                                  const int* __restrict__ locincl,
                                                  const int* __restrict__ bsum,
                                                  int* __restrict__ rowptr,
                                                  int* __restrict__ cursor, int N, int E) {
    const int i = blockIdx.x * 256 + threadIdx.x;
    if (i < N) {
        int excl = bsum[blockIdx.x] + locincl[i] - deg[i];
        rowptr[i] = excl;
        cursor[i] = excl;
    }
    if (i == 0) rowptr[N] = E;
}

__global__ void scatter_kernel(const int* __restrict__ src, const int* __restrict__ dst,
                               int* __restrict__ cursor, int* __restrict__ esrc, int E) {
    int e = blockIdx.x * blockDim.x + threadIdx.x;
    if (e < E) {
        int pos = atomicAdd(&cursor[dst[e]], 1);
        esrc[pos] = src[e];
    }
}

// ---------------- CSR mean-aggregation: wave-per-node, 16B/lane gathers ----------------
__global__ __launch_bounds__(256) void agg_csr(const fp16_t* __restrict__ h,
                                               const int* __restrict__ rowptr,
                                               const int* __restrict__ esrc,
                                               fp16_t* __restrict__ mean, int N) {
    const int n = blockIdx.x * 4 + (threadIdx.x >> 6);
    if (n >= N) return;
    const int lane = threadIdx.x & 63;
    const int half = lane >> 5;         // 0 or 1
    const int l32 = lane & 31;          // channel group 0..31 (8 ch each)
    const int r0 = rowptr[n];
    const int r1 = rowptr[n + 1];
    const int deg = r1 - r0;

    float acc[8];
#pragma unroll
    for (int j = 0; j < 8; ++j) acc[j] = 0.f;

    for (int e = r0 + half; e < r1; e += 2) {
        int s = esrc[e];
        half8 v = *(const half8*)&h[(size_t)s * HID + l32 * 8];
#pragma unroll
        for (int j = 0; j < 8; ++j) acc[j] += (float)v[j];
    }
#pragma unroll
    for (int j = 0; j < 8; ++j) acc[j] += __shfl(acc[j], lane ^ 32, 64);

    if (half == 0) {
        float inv = 1.0f / fmaxf((float)deg, 1.0f);
        half8 o;
#pragma unroll
        for (int j = 0; j < 8; ++j) o[j] = (fp16_t)(acc[j] * inv);
        *(half8*)&mean[(size_t)n * HID + l32 * 8] = o;
    }
}

// ---------------- Final linear: out[N,12] = h[N,128] @ W[128,12] + b ----------------
__global__ void lin_final(const float* __restrict__ X, const float* __restrict__ W,
                          const float* __restrict__ b, float* __restrict__ Y, int N) {
    int idx = blockIdx.x * blockDim.x + threadIdx.x;
    if (idx >= N * OUT_DIM) return;
    int row = idx / OUT_DIM;
    int j = idx - row * OUT_DIM;
    float acc = b[j];
#pragma unroll 8
    for (int k = 0; k < 128; ++k)
        acc = fmaf(X[row * 128 + k], W[k * OUT_DIM + j], acc);
    Y[idx] = acc;
}

extern "C" void kernel_launch(void* const* d_in, const int* in_sizes, int n_in,
                              void* d_out, int out_size, void* d_ws, size_t ws_size,
                              hipStream_t stream) {
    const float* x      = (const float*)d_in[0];
    const int*   eidx   = (const int*)d_in[1];
    const float* enc_w1 = (const float*)d_in[2];
    const float* enc_b1 = (const float*)d_in[3];
    const float* enc_w2 = (const float*)d_in[4];
    const float* enc_b2 = (const float*)d_in[5];
    const float* s1_wl  = (const float*)d_in[6];
    const float* s1_bl  = (const float*)d_in[7];
    const float* s1_wr  = (const float*)d_in[8];
    const float* s2_wl  = (const float*)d_in[9];
    const float* s2_bl  = (const float*)d_in[10];
    const float* s2_wr  = (const float*)d_in[11];
    const float* ro_w1  = (const float*)d_in[12];
    const float* ro_b1  = (const float*)d_in[13];
    const float* ro_w2  = (const float*)d_in[14];
    const float* ro_b2  = (const float*)d_in[15];
    float* out = (float*)d_out;

    const int N = N_NODES;
    const int E = N_EDGES;
    const int* src = eidx;
    const int* dst = eidx + E;

    char* ws = (char*)d_ws;
    size_t off = 0;
    auto alloc = [&](size_t bytes) { void* p = ws + off; off += (bytes + 255) & ~255ULL; return p; };
    int* deg     = (int*)alloc((size_t)N * 4);
    int* rowptr  = (int*)alloc((size_t)(N + 1) * 4);
    int* cursor  = (int*)alloc((size_t)N * 4);
    int* esrc    = (int*)alloc((size_t)E * 4);
    int* locincl = (int*)alloc((size_t)N * 4);
    int* bsum    = (int*)alloc((size_t)256 * 4);
    fp16_t* wtE_hi  = (fp16_t*)alloc((size_t)256 * 128 * 2);
    fp16_t* wtE_lo  = (fp16_t*)alloc((size_t)256 * 128 * 2);
    fp16_t* wtS1_hi = (fp16_t*)alloc((size_t)256 * 512 * 2);
    fp16_t* wtS1_lo = (fp16_t*)alloc((size_t)256 * 512 * 2);
    fp16_t* wtS2_hi = (fp16_t*)alloc((size_t)256 * 512 * 2);
    fp16_t* wtS2_lo = (fp16_t*)alloc((size_t)256 * 512 * 2);
    fp16_t* wtR_hi  = (fp16_t*)alloc((size_t)128 * 256 * 2);
    fp16_t* wtR_lo  = (fp16_t*)alloc((size_t)128 * 256 * 2);
    fp16_t* h0   = (fp16_t*)alloc((size_t)N * 128 * 2);
    float* f32buf = (float*)alloc((size_t)N * 128 * 4);
    fp16_t* hA   = (fp16_t*)alloc((size_t)N * HID * 2);
    fp16_t* hB   = (fp16_t*)alloc((size_t)N * HID * 2);
    fp16_t* mbuf = (fp16_t*)alloc((size_t)N * HID * 2);

    const int nb8 = (N + 7) / 8;
    const int gx64 = (N + 63) / 64;
    const int gx128 = (N + 127) / 128;
    const int nbScan = (N + 255) / 256;
    const int nbAgg = (N + 3) / 4;
    const int wtTot = 256 * 128 + 2 * 256 * 512 + 128 * 256;

    // ---- CSR build ----
    zero_kernel<<<(N + 1023) / 1024, 1024, 0, stream>>>(deg, N);
    deg_kernel<<<(E + 255) / 256, 256, 0, stream>>>(dst, deg, E);
    scan_local<<<nbScan, 256, 0, stream>>>(deg, locincl, bsum, N);
    scan_bsum<<<1, 256, 0, stream>>>(bsum, nbScan);
    scan_final<<<nbScan, 256, 0, stream>>>(deg, locincl, bsum, rowptr, cursor, N, E);
    scatter_kernel<<<(E + 255) / 256, 256, 0, stream>>>(src, dst, cursor, esrc, E);

    // ---- weight transpose + split (single fused launch) ----
    wtrans_all<<<(wtTot + 255) / 256, 256, 0, stream>>>(
        enc_w2, s1_wl, s1_wr, s2_wl, s2_wr, ro_w1,
        wtE_hi, wtE_lo, wtS1_hi, wtS1_lo, wtS2_hi, wtS2_lo, wtR_hi, wtR_lo);

    // ---- encoder ----
    lin_enc1<IN_DIM, 128, 8><<<nb8, 128, 0, stream>>>(x, enc_w1, enc_b1, h0, N);
    gemm_mfma<128, 0, 64, 256, false, true, true><<<dim3(gx64, 1), 256, 0, stream>>>(
        h0, nullptr, wtE_hi, wtE_lo, enc_b2, nullptr, hA, N, 256);

    // ---- SAGE 1 ----
    agg_csr<<<nbAgg, 256, 0, stream>>>(hA, rowptr, esrc, mbuf, N);
    gemm_mfma<512, 1, 64, 256, false, true, true><<<dim3(gx64, 1), 256, 0, stream>>>(
        mbuf, hA, wtS1_hi, wtS1_lo, s1_bl, nullptr, hB, N, 256);

    // ---- SAGE 2 ----
    agg_csr<<<nbAgg, 256, 0, stream>>>(hB, rowptr, esrc, mbuf, N);
    gemm_mfma<512, 1, 64, 256, false, true, true><<<dim3(gx64, 1), 256, 0, stream>>>(
        mbuf, hB, wtS2_hi, wtS2_lo, s2_bl, nullptr, hA, N, 256);

    // ---- readout ----
    gemm_mfma<256, 0, 128, 128, true, false, true><<<dim3(gx128, 1), 256, 0, stream>>>(
        hA, nullptr, wtR_hi, wtR_lo, ro_b1, f32buf, nullptr, N, 128);
    lin_final<<<(N * OUT_DIM + 255) / 256, 256, 0, stream>>>(f32buf, ro_w2, ro_b2, out, N);
}

// Round 11
// 297.924 us; speedup vs baseline: 1.1570x; 1.1570x over previous
//
#include <hip/hip_runtime.h>
#include <hip/hip_bf16.h>

#define N_NODES 50000
#define N_EDGES 400000
#define IN_DIM 24
#define HID 256
#define OUT_DIM 12

typedef _Float16 fp16_t;
typedef __attribute__((ext_vector_type(8))) _Float16 half8;
typedef __attribute__((ext_vector_type(4))) float f32x4;

// async global->LDS, 16 bytes per lane (dest must be linear: base + lane*16 per wave)
__device__ __forceinline__ void gload_lds16(const void* g, void* l) {
    typedef __attribute__((address_space(3))) unsigned int u32_lds;
    typedef const __attribute__((address_space(1))) unsigned int u32_glb;
    __builtin_amdgcn_global_load_lds((u32_glb*)(unsigned long long)g,
                                     (u32_lds*)(unsigned int)(unsigned long long)l,
                                     16, 0, 0);
}

// ---------------- encoder layer 1 (K=24, f32 compute, fp16 out) ----------------
template<int K, int M, int ROWS>
__global__ __launch_bounds__(M) void lin_enc1(const float* __restrict__ X,
                                              const float* __restrict__ W,
                                              const float* __restrict__ b,
                                              fp16_t* __restrict__ Y, int N) {
    __shared__ float xs[ROWS][K];
    const int row0 = blockIdx.x * ROWS;
    const int tid = threadIdx.x;
    for (int i = tid; i < ROWS * K; i += M) {
        int r = i / K, k = i - r * K;
        int gr = row0 + r;
        xs[r][k] = (gr < N) ? X[(long long)gr * K + k] : 0.f;
    }
    __syncthreads();
    const int j = tid;
    float acc[ROWS];
    float bj = b[j];
#pragma unroll
    for (int r = 0; r < ROWS; ++r) acc[r] = bj;
    for (int k = 0; k < K; ++k) {
        float w = W[k * M + j];
#pragma unroll
        for (int r = 0; r < ROWS; ++r) acc[r] = fmaf(xs[r][k], w, acc[r]);
    }
#pragma unroll
    for (int r = 0; r < ROWS; ++r) {
        int gr = row0 + r;
        if (gr < N) {
            float v = fmaxf(acc[r], 0.f);
            Y[(size_t)gr * M + j] = (fp16_t)v;
        }
    }
}

// ---------------- fused weight transpose + fp16 hi/lo split (all 4 weight sets) ----------------
__global__ __launch_bounds__(256) void wtrans_all(
    const float* __restrict__ enc_w2,
    const float* __restrict__ s1_wl, const float* __restrict__ s1_wr,
    const float* __restrict__ s2_wl, const float* __restrict__ s2_wr,
    const float* __restrict__ ro_w1,
    fp16_t* __restrict__ wtE_hi, fp16_t* __restrict__ wtE_lo,
    fp16_t* __restrict__ wtS1_hi, fp16_t* __restrict__ wtS1_lo,
    fp16_t* __restrict__ wtS2_hi, fp16_t* __restrict__ wtS2_lo,
    fp16_t* __restrict__ wtR_hi, fp16_t* __restrict__ wtR_lo) {
    const int sE = 256 * 128, sS = 256 * 512, sR = 128 * 256;
    int idx = blockIdx.x * blockDim.x + threadIdx.x;
    float v; fp16_t *ph, *pl; int o;
    if (idx < sE) {
        int j = idx / 128, k = idx - j * 128;
        v = enc_w2[(size_t)k * 256 + j]; ph = wtE_hi; pl = wtE_lo; o = idx;
    } else if (idx < sE + sS) {
        int t = idx - sE; int j = t / 512, k = t - j * 512;
        v = (k < 256) ? s1_wl[(size_t)k * 256 + j] : s1_wr[(size_t)(k - 256) * 256 + j];
        ph = wtS1_hi; pl = wtS1_lo; o = t;
    } else if (idx < sE + 2 * sS) {
        int t = idx - sE - sS; int j = t / 512, k = t - j * 512;
        v = (k < 256) ? s2_wl[(size_t)k * 256 + j] : s2_wr[(size_t)(k - 256) * 256 + j];
        ph = wtS2_hi; pl = wtS2_lo; o = t;
    } else if (idx < sE + 2 * sS + sR) {
        int t = idx - sE - 2 * sS; int j = t / 256, k = t - j * 256;
        v = ro_w1[(size_t)k * 128 + j]; ph = wtR_hi; pl = wtR_lo; o = t;
    } else return;
    fp16_t h = (fp16_t)v;
    ph[o] = h;
    pl[o] = (fp16_t)(v - (float)h);
}

// ---------------- MFMA fp16 GEMM, double-buffered 2-phase pipeline ----------------
// Block tile BM x BN, BK=32. Waves (BM/64)x(BN/64), wave tile 64x64 (4x4 frags 16x16x32).
// LDS 16B-chunk swizzle: physical slot p of row holds logical chunk (p-(row>>1))&3, applied
// on the GLOBAL source address (gload_lds dest stays linear); frag read uses
// slot=(lg+(row>>1))&3 -> each 16-lane ds_read_b128 phase is <=2-way on banks (free).
// Pipeline: STAGE(next) issued BEFORE compute(cur); single barrier per K-tile drains both.
// MODE 0: A rows from A [N][K];  MODE 1: k<HID from A (mean), else A2 (h), both [N][HID]
template<int K, int MODE, int BM, int BN, bool WF32, bool WH16, bool RELU>
__global__ __launch_bounds__((BM / 64) * (BN / 64) * 64, 4) void gemm_mfma(
    const fp16_t* __restrict__ A, const fp16_t* __restrict__ A2,
    const fp16_t* __restrict__ Whi, const fp16_t* __restrict__ Wlo,
    const float* __restrict__ bias,
    float* __restrict__ Yf, fp16_t* __restrict__ Yh,
    int N, int M) {
    constexpr int NWR = BM / 64;
    constexpr int NWC = BN / 64;
    constexpr int NT = NWR * NWC * 64;
    __shared__ __align__(16) fp16_t ldsA[2][BM * 32];
    __shared__ __align__(16) fp16_t ldsBh[2][BN * 32];
    __shared__ __align__(16) fp16_t ldsBl[2][BN * 32];
    const int tid = threadIdx.x;
    const int r0 = blockIdx.x * BM;
    const int j0 = blockIdx.y * BN;
    const int w = tid >> 6, lane = tid & 63;
    const int wr = w / NWC, wc = w % NWC;
    const int lrow = lane & 15, lg = lane >> 4;

    f32x4 acc[4][4] = {};

    auto stage = [&](int buf, int kc) {
        const fp16_t* pa; int ka, KA;
        if (MODE == 1) {
            KA = HID;
            if (kc >= HID) { pa = A2; ka = kc - HID; }
            else           { pa = A;  ka = kc; }
        } else {
            KA = K; pa = A; ka = kc;
        }
#pragma unroll
        for (int c = tid; c < BM * 4; c += NT) {
            int row = c >> 2, p = c & 3;
            int g = (p - (row >> 1)) & 3;           // inverse swizzle on source
            int gr = r0 + row; if (gr > N - 1) gr = N - 1;
            gload_lds16(pa + (size_t)gr * KA + ka + g * 8,
                        (char*)&ldsA[buf][0] + (size_t)c * 16);
        }
#pragma unroll
        for (int c = tid; c < BN * 4; c += NT) {
            int row = c >> 2, p = c & 3;
            int g = (p - (row >> 1)) & 3;
            size_t go = (size_t)(j0 + row) * K + kc + g * 8;
            gload_lds16(Whi + go, (char*)&ldsBh[buf][0] + (size_t)c * 16);
            gload_lds16(Wlo + go, (char*)&ldsBl[buf][0] + (size_t)c * 16);
        }
    };

    stage(0, 0);
    __syncthreads();
    int cur = 0;

    for (int kc = 0; kc < K; kc += 32) {
        if (kc + 32 < K) stage(cur ^ 1, kc + 32);   // prefetch flies under MFMA

        half8 a[4], bh[4], bl[4];
#pragma unroll
        for (int f = 0; f < 4; ++f) {
            int ar = wr * 64 + f * 16 + lrow;
            int sa = (lg + (ar >> 1)) & 3;
            a[f] = *(const half8*)&ldsA[cur][ar * 32 + sa * 8];
            int br = wc * 64 + f * 16 + lrow;
            int sb = (lg + (br >> 1)) & 3;
            bh[f] = *(const half8*)&ldsBh[cur][br * 32 + sb * 8];
            bl[f] = *(const half8*)&ldsBl[cur][br * 32 + sb * 8];
        }
#pragma unroll
        for (int fi = 0; fi < 4; ++fi)
#pragma unroll
            for (int fj = 0; fj < 4; ++fj) {
                acc[fi][fj] = __builtin_amdgcn_mfma_f32_16x16x32_f16(a[fi], bh[fj], acc[fi][fj], 0, 0, 0);
                acc[fi][fj] = __builtin_amdgcn_mfma_f32_16x16x32_f16(a[fi], bl[fj], acc[fi][fj], 0, 0, 0);
            }
        __syncthreads();   // drains vmcnt (prefetch) + lgkm (frag reads)
        cur ^= 1;
    }

    // ---- epilogue: C/D layout col=lane&15, row=(lane>>4)*4+reg ----
#pragma unroll
    for (int fj = 0; fj < 4; ++fj) {
        int ocol = j0 + wc * 64 + fj * 16 + lrow;
        float bv = bias[ocol];
#pragma unroll
        for (int fi = 0; fi < 4; ++fi) {
#pragma unroll
            for (int r = 0; r < 4; ++r) {
                int orow = r0 + wr * 64 + fi * 16 + lg * 4 + r;
                if (orow < N) {
                    float v = acc[fi][fj][r] + bv;
                    if (RELU) v = fmaxf(v, 0.f);
                    size_t o = (size_t)orow * M + ocol;
                    if (WF32) Yf[o] = v;
                    if (WH16) Yh[o] = (fp16_t)v;
                }
            }
        }
    }
}

// ---------------- CSR build ----------------
__global__ __launch_bounds__(1024) void zero_kernel(int* __restrict__ p, int n) {
    int i = blockIdx.x * blockDim.x + threadIdx.x;
    if (i < n) p[i] = 0;
}

__global__ void deg_kernel(const int* __restrict__ dst, int* __restrict__ deg, int E) {
    int e = blockIdx.x * blockDim.x + threadIdx.x;
    if (e < E) atomicAdd(&deg[dst[e]], 1);
}

// Stage 1: per-block inclusive scan (256 elems/block) + block total
__global__ __launch_bounds__(256) void scan_local(const int* __restrict__ deg,
                                                  int* __restrict__ locincl,
                                                  int* __restrict__ bsum, int N) {
    const int t = threadIdx.x;
    const int i = blockIdx.x * 256 + t;
    int v = (i < N) ? deg[i] : 0;
    const int lane = t & 63;
    int x = v;
#pragma unroll
    for (int off = 1; off < 64; off <<= 1) {
        int y = __shfl_up(x, off, 64);
        if (lane >= off) x += y;
    }
    __shared__ int wsum[4];
    if (lane == 63) wsum[t >> 6] = x;
    __syncthreads();
    const int wid = t >> 6;
    int add = 0;
    for (int wI = 0; wI < wid; ++wI) add += wsum[wI];
    x += add;
    if (i < N) locincl[i] = x;
    if (t == 255) bsum[blockIdx.x] = x;
}

// Stage 2: exclusive scan of block sums (B <= 256), single block
__global__ __launch_bounds__(256) void scan_bsum(int* __restrict__ bsum, int B) {
    const int t = threadIdx.x;
    int v = (t < B) ? bsum[t] : 0;
    const int lane = t & 63;
    int x = v;
#pragma unroll
    for (int off = 1; off < 64; off <<= 1) {
        int y = __shfl_up(x, off, 64);
        if (lane >= off) x += y;
    }
    __shared__ int wsum[4];
    if (lane == 63) wsum[t >> 6] = x;
    __syncthreads();
    const int wid = t >> 6;
    int add = 0;
    for (int wI = 0; wI < wid; ++wI) add += wsum[wI];
    x += add;
    if (t < B) bsum[t] = x - v;   // exclusive
}

// Stage 3: recombine -> exclusive rowptr + cursor
__global__ __launch_bounds__(256) void scan_final(const int* __restrict__ deg,
                                                  const int* __restrict__ locincl,
                                                  const int* __restrict__ bsum,
                                                  int* __restrict__ rowptr,
                                                  int* __restrict__ cursor, int N, int E) {
    const int i = blockIdx.x * 256 + threadIdx.x;
    if (i < N) {
        int excl = bsum[blockIdx.x] + locincl[i] - deg[i];
        rowptr[i] = excl;
        cursor[i] = excl;
    }
    if (i == 0) rowptr[N] = E;
}

__global__ void scatter_kernel(const int* __restrict__ src, const int* __restrict__ dst,
                               int* __restrict__ cursor, int* __restrict__ esrc, int E) {
    int e = blockIdx.x * blockDim.x + threadIdx.x;
    if (e < E) {
        int pos = atomicAdd(&cursor[dst[e]], 1);
        esrc[pos] = src[e];
    }
}

// ---------------- CSR mean-aggregation: wave-per-node, 16B/lane gathers ----------------
__global__ __launch_bounds__(256) void agg_csr(const fp16_t* __restrict__ h,
                                               const int* __restrict__ rowptr,
                                               const int* __restrict__ esrc,
                                               fp16_t* __restrict__ mean, int N) {
    const int n = blockIdx.x * 4 + (threadIdx.x >> 6);
    if (n >= N) return;
    const int lane = threadIdx.x & 63;
    const int half = lane >> 5;         // 0 or 1
    const int l32 = lane & 31;          // channel group 0..31 (8 ch each)
    const int r0 = rowptr[n];
    const int r1 = rowptr[n + 1];
    const int deg = r1 - r0;

    float acc[8];
#pragma unroll
    for (int j = 0; j < 8; ++j) acc[j] = 0.f;

    for (int e = r0 + half; e < r1; e += 2) {
        int s = esrc[e];
        half8 v = *(const half8*)&h[(size_t)s * HID + l32 * 8];
#pragma unroll
        for (int j = 0; j < 8; ++j) acc[j] += (float)v[j];
    }
#pragma unroll
    for (int j = 0; j < 8; ++j) acc[j] += __shfl(acc[j], lane ^ 32, 64);

    if (half == 0) {
        float inv = 1.0f / fmaxf((float)deg, 1.0f);
        half8 o;
#pragma unroll
        for (int j = 0; j < 8; ++j) o[j] = (fp16_t)(acc[j] * inv);
        *(half8*)&mean[(size_t)n * HID + l32 * 8] = o;
    }
}

// ---------------- Final linear: out[N,12] = h[N,128] @ W[128,12] + b ----------------
__global__ void lin_final(const float* __restrict__ X, const float* __restrict__ W,
                          const float* __restrict__ b, float* __restrict__ Y, int N) {
    int idx = blockIdx.x * blockDim.x + threadIdx.x;
    if (idx >= N * OUT_DIM) return;
    int row = idx / OUT_DIM;
    int j = idx - row * OUT_DIM;
    float acc = b[j];
#pragma unroll 8
    for (int k = 0; k < 128; ++k)
        acc = fmaf(X[row * 128 + k], W[k * OUT_DIM + j], acc);
    Y[idx] = acc;
}

extern "C" void kernel_launch(void* const* d_in, const int* in_sizes, int n_in,
                              void* d_out, int out_size, void* d_ws, size_t ws_size,
                              hipStream_t stream) {
    const float* x      = (const float*)d_in[0];
    const int*   eidx   = (const int*)d_in[1];
    const float* enc_w1 = (const float*)d_in[2];
    const float* enc_b1 = (const float*)d_in[3];
    const float* enc_w2 = (const float*)d_in[4];
    const float* enc_b2 = (const float*)d_in[5];
    const float* s1_wl  = (const float*)d_in[6];
    const float* s1_bl  = (const float*)d_in[7];
    const float* s1_wr  = (const float*)d_in[8];
    const float* s2_wl  = (const float*)d_in[9];
    const float* s2_bl  = (const float*)d_in[10];
    const float* s2_wr  = (const float*)d_in[11];
    const float* ro_w1  = (const float*)d_in[12];
    const float* ro_b1  = (const float*)d_in[13];
    const float* ro_w2  = (const float*)d_in[14];
    const float* ro_b2  = (const float*)d_in[15];
    float* out = (float*)d_out;

    const int N = N_NODES;
    const int E = N_EDGES;
    const int* src = eidx;
    const int* dst = eidx + E;

    char* ws = (char*)d_ws;
    size_t off = 0;
    auto alloc = [&](size_t bytes) { void* p = ws + off; off += (bytes + 255) & ~255ULL; return p; };
    int* deg     = (int*)alloc((size_t)N * 4);
    int* rowptr  = (int*)alloc((size_t)(N + 1) * 4);
    int* cursor  = (int*)alloc((size_t)N * 4);
    int* esrc    = (int*)alloc((size_t)E * 4);
    int* locincl = (int*)alloc((size_t)N * 4);
    int* bsum    = (int*)alloc((size_t)256 * 4);
    fp16_t* wtE_hi  = (fp16_t*)alloc((size_t)256 * 128 * 2);
    fp16_t* wtE_lo  = (fp16_t*)alloc((size_t)256 * 128 * 2);
    fp16_t* wtS1_hi = (fp16_t*)alloc((size_t)256 * 512 * 2);
    fp16_t* wtS1_lo = (fp16_t*)alloc((size_t)256 * 512 * 2);
    fp16_t* wtS2_hi = (fp16_t*)alloc((size_t)256 * 512 * 2);
    fp16_t* wtS2_lo = (fp16_t*)alloc((size_t)256 * 512 * 2);
    fp16_t* wtR_hi  = (fp16_t*)alloc((size_t)128 * 256 * 2);
    fp16_t* wtR_lo  = (fp16_t*)alloc((size_t)128 * 256 * 2);
    fp16_t* h0   = (fp16_t*)alloc((size_t)N * 128 * 2);
    float* f32buf = (float*)alloc((size_t)N * 128 * 4);
    fp16_t* hA   = (fp16_t*)alloc((size_t)N * HID * 2);
    fp16_t* hB   = (fp16_t*)alloc((size_t)N * HID * 2);
    fp16_t* mbuf = (fp16_t*)alloc((size_t)N * HID * 2);

    const int nb8 = (N + 7) / 8;
    const int gx128 = (N + 127) / 128;
    const int nbScan = (N + 255) / 256;
    const int nbAgg = (N + 3) / 4;
    const int wtTot = 256 * 128 + 2 * 256 * 512 + 128 * 256;

    // ---- CSR build ----
    zero_kernel<<<(N + 1023) / 1024, 1024, 0, stream>>>(deg, N);
    deg_kernel<<<(E + 255) / 256, 256, 0, stream>>>(dst, deg, E);
    scan_local<<<nbScan, 256, 0, stream>>>(deg, locincl, bsum, N);
    scan_bsum<<<1, 256, 0, stream>>>(bsum, nbScan);
    scan_final<<<nbScan, 256, 0, stream>>>(deg, locincl, bsum, rowptr, cursor, N, E);
    scatter_kernel<<<(E + 255) / 256, 256, 0, stream>>>(src, dst, cursor, esrc, E);

    // ---- weight transpose + split (single fused launch) ----
    wtrans_all<<<(wtTot + 255) / 256, 256, 0, stream>>>(
        enc_w2, s1_wl, s1_wr, s2_wl, s2_wr, ro_w1,
        wtE_hi, wtE_lo, wtS1_hi, wtS1_lo, wtS2_hi, wtS2_lo, wtR_hi, wtR_lo);

    // ---- encoder ----
    lin_enc1<IN_DIM, 128, 8><<<nb8, 128, 0, stream>>>(x, enc_w1, enc_b1, h0, N);
    gemm_mfma<128, 0, 128, 256, false, true, true><<<dim3(gx128, 1), 512, 0, stream>>>(
        h0, nullptr, wtE_hi, wtE_lo, enc_b2, nullptr, hA, N, 256);

    // ---- SAGE 1 ----
    agg_csr<<<nbAgg, 256, 0, stream>>>(hA, rowptr, esrc, mbuf, N);
    gemm_mfma<512, 1, 128, 256, false, true, true><<<dim3(gx128, 1), 512, 0, stream>>>(
        mbuf, hA, wtS1_hi, wtS1_lo, s1_bl, nullptr, hB, N, 256);

    // ---- SAGE 2 ----
    agg_csr<<<nbAgg, 256, 0, stream>>>(hB, rowptr, esrc, mbuf, N);
    gemm_mfma<512, 1, 128, 256, false, true, true><<<dim3(gx128, 1), 512, 0, stream>>>(
        mbuf, hB, wtS2_hi, wtS2_lo, s2_bl, nullptr, hA, N, 256);

    // ---- readout ----
    gemm_mfma<256, 0, 128, 128, true, false, true><<<dim3(gx128, 1), 256, 0, stream>>>(
        hA, nullptr, wtR_hi, wtR_lo, ro_b1, f32buf, nullptr, N, 128);
    lin_final<<<(N * OUT_DIM + 255) / 256, 256, 0, stream>>>(f32buf, ro_w2, ro_b2, out, N);
}

// Round 12
// 259.462 us; speedup vs baseline: 1.3285x; 1.1482x over previous
//
#include <hip/hip_runtime.h>
#include <hip/hip_bf16.h>

#define N_NODES 50000
#define N_EDGES 400000
#define IN_DIM 24
#define HID 256
#define OUT_DIM 12

typedef _Float16 fp16_t;
typedef __attribute__((ext_vector_type(8))) _Float16 half8;
typedef __attribute__((ext_vector_type(4))) float f32x4;

// async global->LDS, 16 bytes per lane (dest must be linear: base + lane*16 per wave)
__device__ __forceinline__ void gload_lds16(const void* g, void* l) {
    typedef __attribute__((address_space(3))) unsigned int u32_lds;
    typedef const __attribute__((address_space(1))) unsigned int u32_glb;
    __builtin_amdgcn_global_load_lds((u32_glb*)(unsigned long long)g,
                                     (u32_lds*)(unsigned int)(unsigned long long)l,
                                     16, 0, 0);
}

// ---------------- encoder layer 1 (K=24, f32 compute, fp16 out) ----------------
template<int K, int M, int ROWS>
__global__ __launch_bounds__(M) void lin_enc1(const float* __restrict__ X,
                                              const float* __restrict__ W,
                                              const float* __restrict__ b,
                                              fp16_t* __restrict__ Y, int N) {
    __shared__ float xs[ROWS][K];
    const int row0 = blockIdx.x * ROWS;
    const int tid = threadIdx.x;
    for (int i = tid; i < ROWS * K; i += M) {
        int r = i / K, k = i - r * K;
        int gr = row0 + r;
        xs[r][k] = (gr < N) ? X[(long long)gr * K + k] : 0.f;
    }
    __syncthreads();
    const int j = tid;
    float acc[ROWS];
    float bj = b[j];
#pragma unroll
    for (int r = 0; r < ROWS; ++r) acc[r] = bj;
    for (int k = 0; k < K; ++k) {
        float w = W[k * M + j];
#pragma unroll
        for (int r = 0; r < ROWS; ++r) acc[r] = fmaf(xs[r][k], w, acc[r]);
    }
#pragma unroll
    for (int r = 0; r < ROWS; ++r) {
        int gr = row0 + r;
        if (gr < N) {
            float v = fmaxf(acc[r], 0.f);
            Y[(size_t)gr * M + j] = (fp16_t)v;
        }
    }
}

// ---------------- fused weight transpose to fp16 (all 4 weight sets, single plane) ----------------
__global__ __launch_bounds__(256) void wtrans_all(
    const float* __restrict__ enc_w2,
    const float* __restrict__ s1_wl, const float* __restrict__ s1_wr,
    const float* __restrict__ s2_wl, const float* __restrict__ s2_wr,
    const float* __restrict__ ro_w1,
    fp16_t* __restrict__ wtE,
    fp16_t* __restrict__ wtS1,
    fp16_t* __restrict__ wtS2,
    fp16_t* __restrict__ wtR) {
    const int sE = 256 * 128, sS = 256 * 512, sR = 128 * 256;
    int idx = blockIdx.x * blockDim.x + threadIdx.x;
    float v; fp16_t* p; int o;
    if (idx < sE) {
        int j = idx / 128, k = idx - j * 128;
        v = enc_w2[(size_t)k * 256 + j]; p = wtE; o = idx;
    } else if (idx < sE + sS) {
        int t = idx - sE; int j = t / 512, k = t - j * 512;
        v = (k < 256) ? s1_wl[(size_t)k * 256 + j] : s1_wr[(size_t)(k - 256) * 256 + j];
        p = wtS1; o = t;
    } else if (idx < sE + 2 * sS) {
        int t = idx - sE - sS; int j = t / 512, k = t - j * 512;
        v = (k < 256) ? s2_wl[(size_t)k * 256 + j] : s2_wr[(size_t)(k - 256) * 256 + j];
        p = wtS2; o = t;
    } else if (idx < sE + 2 * sS + sR) {
        int t = idx - sE - 2 * sS; int j = t / 256, k = t - j * 256;
        v = ro_w1[(size_t)k * 128 + j]; p = wtR; o = t;
    } else return;
    p[o] = (fp16_t)v;
}

// ---------------- MFMA fp16 GEMM (single weight plane) ----------------
// Block tile BM x BN, BK=32. Waves (BM/64)x(BN/64), wave tile 64x64 (4x4 frags 16x16x32).
// LDS 16B-chunk swizzle (verified R11, conflicts->0): physical slot p of row holds logical
// chunk (p-(row>>1))&3 applied on the GLOBAL source (gload_lds dest stays linear);
// frag read uses slot=(lg+(row>>1))&3 -> ds_read_b128 phases are <=2-way on banks (free).
// Proven R9 2-barrier loop; cross-block TLP (4 blocks/CU at 24KB LDS) hides load latency.
// MODE 0: A rows from A [N][K];  MODE 1: k<HID from A (mean), else A2 (h), both [N][HID]
template<int K, int MODE, int BM, int BN, bool WF32, bool WH16, bool RELU>
__global__ __launch_bounds__((BM / 64) * (BN / 64) * 64, 4) void gemm_mfma(
    const fp16_t* __restrict__ A, const fp16_t* __restrict__ A2,
    const fp16_t* __restrict__ W,
    const float* __restrict__ bias,
    float* __restrict__ Yf, fp16_t* __restrict__ Yh,
    int N, int M) {
    constexpr int NWR = BM / 64;
    constexpr int NWC = BN / 64;
    constexpr int NT = NWR * NWC * 64;
    __shared__ __align__(16) fp16_t ldsA[BM * 32];
    __shared__ __align__(16) fp16_t ldsB[BN * 32];
    const int tid = threadIdx.x;
    const int r0 = blockIdx.x * BM;
    const int j0 = blockIdx.y * BN;
    const int w = tid >> 6, lane = tid & 63;
    const int wr = w / NWC, wc = w % NWC;
    const int lrow = lane & 15, lg = lane >> 4;

    f32x4 acc[4][4] = {};

    for (int kc = 0; kc < K; kc += 32) {
        __syncthreads();   // waves done reading previous tile
        // ---- stage A tile (BM x 32), source column inverse-swizzled ----
        const fp16_t* pa;
        int ka, KA;
        if (MODE == 1) {
            KA = HID;
            if (kc >= HID) { pa = A2; ka = kc - HID; }
            else           { pa = A;  ka = kc; }
        } else {
            KA = K; pa = A; ka = kc;
        }
#pragma unroll
        for (int c = tid; c < BM * 4; c += NT) {
            int row = c >> 2, p = c & 3;
            int g = (p - (row >> 1)) & 3;
            int gr = r0 + row; if (gr > N - 1) gr = N - 1;
            gload_lds16(pa + (size_t)gr * KA + ka + g * 8,
                        (char*)ldsA + (size_t)c * 16);
        }
        // ---- stage B tile (BN x 32) ----
#pragma unroll
        for (int c = tid; c < BN * 4; c += NT) {
            int row = c >> 2, p = c & 3;
            int g = (p - (row >> 1)) & 3;
            gload_lds16(W + (size_t)(j0 + row) * K + kc + g * 8,
                        (char*)ldsB + (size_t)c * 16);
        }
        __syncthreads();   // loads visible

        half8 a[4], b[4];
#pragma unroll
        for (int f = 0; f < 4; ++f) {
            int ar = wr * 64 + f * 16 + lrow;
            int sa = (lg + (ar >> 1)) & 3;
            a[f] = *(const half8*)&ldsA[ar * 32 + sa * 8];
            int br = wc * 64 + f * 16 + lrow;
            int sb = (lg + (br >> 1)) & 3;
            b[f] = *(const half8*)&ldsB[br * 32 + sb * 8];
        }
#pragma unroll
        for (int fi = 0; fi < 4; ++fi)
#pragma unroll
            for (int fj = 0; fj < 4; ++fj)
                acc[fi][fj] = __builtin_amdgcn_mfma_f32_16x16x32_f16(a[fi], b[fj], acc[fi][fj], 0, 0, 0);
    }

    // ---- epilogue: C/D layout col=lane&15, row=(lane>>4)*4+reg ----
#pragma unroll
    for (int fj = 0; fj < 4; ++fj) {
        int ocol = j0 + wc * 64 + fj * 16 + lrow;
        float bv = bias[ocol];
#pragma unroll
        for (int fi = 0; fi < 4; ++fi) {
#pragma unroll
            for (int r = 0; r < 4; ++r) {
                int orow = r0 + wr * 64 + fi * 16 + lg * 4 + r;
                if (orow < N) {
                    float v = acc[fi][fj][r] + bv;
                    if (RELU) v = fmaxf(v, 0.f);
                    size_t o = (size_t)orow * M + ocol;
                    if (WF32) Yf[o] = v;
                    if (WH16) Yh[o] = (fp16_t)v;
                }
            }
        }
    }
}

// ---------------- CSR build ----------------
__global__ __launch_bounds__(1024) void zero_kernel(int* __restrict__ p, int n) {
    int i = blockIdx.x * blockDim.x + threadIdx.x;
    if (i < n) p[i] = 0;
}

__global__ void deg_kernel(const int* __restrict__ dst, int* __restrict__ deg, int E) {
    int e = blockIdx.x * blockDim.x + threadIdx.x;
    if (e < E) atomicAdd(&deg[dst[e]], 1);
}

// Stage 1: per-block inclusive scan (256 elems/block) + block total
__global__ __launch_bounds__(256) void scan_local(const int* __restrict__ deg,
                                                  int* __restrict__ locincl,
                                                  int* __restrict__ bsum, int N) {
    const int t = threadIdx.x;
    const int i = blockIdx.x * 256 + t;
    int v = (i < N) ? deg[i] : 0;
    const int lane = t & 63;
    int x = v;
#pragma unroll
    for (int off = 1; off < 64; off <<= 1) {
        int y = __shfl_up(x, off, 64);
        if (lane >= off) x += y;
    }
    __shared__ int wsum[4];
    if (lane == 63) wsum[t >> 6] = x;
    __syncthreads();
    const int wid = t >> 6;
    int add = 0;
    for (int wI = 0; wI < wid; ++wI) add += wsum[wI];
    x += add;
    if (i < N) locincl[i] = x;
    if (t == 255) bsum[blockIdx.x] = x;
}

// Stage 2: exclusive scan of block sums (B <= 256), single block
__global__ __launch_bounds__(256) void scan_bsum(int* __restrict__ bsum, int B) {
    const int t = threadIdx.x;
    int v = (t < B) ? bsum[t] : 0;
    const int lane = t & 63;
    int x = v;
#pragma unroll
    for (int off = 1; off < 64; off <<= 1) {
        int y = __shfl_up(x, off, 64);
        if (lane >= off) x += y;
    }
    __shared__ int wsum[4];
    if (lane == 63) wsum[t >> 6] = x;
    __syncthreads();
    const int wid = t >> 6;
    int add = 0;
    for (int wI = 0; wI < wid; ++wI) add += wsum[wI];
    x += add;
    if (t < B) bsum[t] = x - v;   // exclusive
}

// Stage 3: recombine -> exclusive rowptr + cursor
__global__ __launch_bounds__(256) void scan_final(const int* __restrict__ deg,
                                                  const int* __restrict__ locincl,
                                                  const int* __restrict__ bsum,
                                                  int* __restrict__ rowptr,
                                                  int* __restrict__ cursor, int N, int E) {
    const int i = blockIdx.x * 256 + threadIdx.x;
    if (i < N) {
        int excl = bsum[blockIdx.x] + locincl[i] - deg[i];
        rowptr[i] = excl;
        cursor[i] = excl;
    }
    if (i == 0) rowptr[N] = E;
}

__global__ void scatter_kernel(const int* __restrict__ src, const int* __restrict__ dst,
                               int* __restrict__ cursor, int* __restrict__ esrc, int E) {
    int e = blockIdx.x * blockDim.x + threadIdx.x;
    if (e < E) {
        int pos = atomicAdd(&cursor[dst[e]], 1);
        esrc[pos] = src[e];
    }
}

// ---------------- CSR mean-aggregation: wave-per-node, 16B/lane gathers ----------------
__global__ __launch_bounds__(256) void agg_csr(const fp16_t* __restrict__ h,
                                               const int* __restrict__ rowptr,
                                               const int* __restrict__ esrc,
                                               fp16_t* __restrict__ mean, int N) {
    const int n = blockIdx.x * 4 + (threadIdx.x >> 6);
    if (n >= N) return;
    const int lane = threadIdx.x & 63;
    const int half = lane >> 5;         // 0 or 1
    const int l32 = lane & 31;          // channel group 0..31 (8 ch each)
    const int r0 = rowptr[n];
    const int r1 = rowptr[n + 1];
    const int deg = r1 - r0;

    float acc[8];
#pragma unroll
    for (int j = 0; j < 8; ++j) acc[j] = 0.f;

    for (int e = r0 + half; e < r1; e += 2) {
        int s = esrc[e];
        half8 v = *(const half8*)&h[(size_t)s * HID + l32 * 8];
#pragma unroll
        for (int j = 0; j < 8; ++j) acc[j] += (float)v[j];
    }
#pragma unroll
    for (int j = 0; j < 8; ++j) acc[j] += __shfl(acc[j], lane ^ 32, 64);

    if (half == 0) {
        float inv = 1.0f / fmaxf((float)deg, 1.0f);
        half8 o;
#pragma unroll
        for (int j = 0; j < 8; ++j) o[j] = (fp16_t)(acc[j] * inv);
        *(half8*)&mean[(size_t)n * HID + l32 * 8] = o;
    }
}

// ---------------- Final linear: out[N,12] = h[N,128] @ W[128,12] + b ----------------
__global__ void lin_final(const float* __restrict__ X, const float* __restrict__ W,
                          const float* __restrict__ b, float* __restrict__ Y, int N) {
    int idx = blockIdx.x * blockDim.x + threadIdx.x;
    if (idx >= N * OUT_DIM) return;
    int row = idx / OUT_DIM;
    int j = idx - row * OUT_DIM;
    float acc = b[j];
#pragma unroll 8
    for (int k = 0; k < 128; ++k)
        acc = fmaf(X[row * 128 + k], W[k * OUT_DIM + j], acc);
    Y[idx] = acc;
}

extern "C" void kernel_launch(void* const* d_in, const int* in_sizes, int n_in,
                              void* d_out, int out_size, void* d_ws, size_t ws_size,
                              hipStream_t stream) {
    const float* x      = (const float*)d_in[0];
    const int*   eidx   = (const int*)d_in[1];
    const float* enc_w1 = (const float*)d_in[2];
    const float* enc_b1 = (const float*)d_in[3];
    const float* enc_w2 = (const float*)d_in[4];
    const float* enc_b2 = (const float*)d_in[5];
    const float* s1_wl  = (const float*)d_in[6];
    const float* s1_bl  = (const float*)d_in[7];
    const float* s1_wr  = (const float*)d_in[8];
    const float* s2_wl  = (const float*)d_in[9];
    const float* s2_bl  = (const float*)d_in[10];
    const float* s2_wr  = (const float*)d_in[11];
    const float* ro_w1  = (const float*)d_in[12];
    const float* ro_b1  = (const float*)d_in[13];
    const float* ro_w2  = (const float*)d_in[14];
    const float* ro_b2  = (const float*)d_in[15];
    float* out = (float*)d_out;

    const int N = N_NODES;
    const int E = N_EDGES;
    const int* src = eidx;
    const int* dst = eidx + E;

    char* ws = (char*)d_ws;
    size_t off = 0;
    auto alloc = [&](size_t bytes) { void* p = ws + off; off += (bytes + 255) & ~255ULL; return p; };
    int* deg     = (int*)alloc((size_t)N * 4);
    int* rowptr  = (int*)alloc((size_t)(N + 1) * 4);
    int* cursor  = (int*)alloc((size_t)N * 4);
    int* esrc    = (int*)alloc((size_t)E * 4);
    int* locincl = (int*)alloc((size_t)N * 4);
    int* bsum    = (int*)alloc((size_t)256 * 4);
    fp16_t* wtE  = (fp16_t*)alloc((size_t)256 * 128 * 2);
    fp16_t* wtS1 = (fp16_t*)alloc((size_t)256 * 512 * 2);
    fp16_t* wtS2 = (fp16_t*)alloc((size_t)256 * 512 * 2);
    fp16_t* wtR  = (fp16_t*)alloc((size_t)128 * 256 * 2);
    fp16_t* h0   = (fp16_t*)alloc((size_t)N * 128 * 2);
    float* f32buf = (float*)alloc((size_t)N * 128 * 4);
    fp16_t* hA   = (fp16_t*)alloc((size_t)N * HID * 2);
    fp16_t* hB   = (fp16_t*)alloc((size_t)N * HID * 2);
    fp16_t* mbuf = (fp16_t*)alloc((size_t)N * HID * 2);

    const int nb8 = (N + 7) / 8;
    const int gx128 = (N + 127) / 128;
    const int nbScan = (N + 255) / 256;
    const int nbAgg = (N + 3) / 4;
    const int wtTot = 256 * 128 + 2 * 256 * 512 + 128 * 256;

    // ---- CSR build ----
    zero_kernel<<<(N + 1023) / 1024, 1024, 0, stream>>>(deg, N);
    deg_kernel<<<(E + 255) / 256, 256, 0, stream>>>(dst, deg, E);
    scan_local<<<nbScan, 256, 0, stream>>>(deg, locincl, bsum, N);
    scan_bsum<<<1, 256, 0, stream>>>(bsum, nbScan);
    scan_final<<<nbScan, 256, 0, stream>>>(deg, locincl, bsum, rowptr, cursor, N, E);
    scatter_kernel<<<(E + 255) / 256, 256, 0, stream>>>(src, dst, cursor, esrc, E);

    // ---- weight transpose (single fused launch, single fp16 plane) ----
    wtrans_all<<<(wtTot + 255) / 256, 256, 0, stream>>>(
        enc_w2, s1_wl, s1_wr, s2_wl, s2_wr, ro_w1, wtE, wtS1, wtS2, wtR);

    // ---- encoder ----
    lin_enc1<IN_DIM, 128, 8><<<nb8, 128, 0, stream>>>(x, enc_w1, enc_b1, h0, N);
    gemm_mfma<128, 0, 128, 256, false, true, true><<<dim3(gx128, 1), 512, 0, stream>>>(
        h0, nullptr, wtE, enc_b2, nullptr, hA, N, 256);

    // ---- SAGE 1 ----
    agg_csr<<<nbAgg, 256, 0, stream>>>(hA, rowptr, esrc, mbuf, N);
    gemm_mfma<512, 1, 128, 256, false, true, true><<<dim3(gx128, 1), 512, 0, stream>>>(
        mbuf, hA, wtS1, s1_bl, nullptr, hB, N, 256);

    // ---- SAGE 2 ----
    agg_csr<<<nbAgg, 256, 0, stream>>>(hB, rowptr, esrc, mbuf, N);
    gemm_mfma<512, 1, 128, 256, false, true, true><<<dim3(gx128, 1), 512, 0, stream>>>(
        mbuf, hB, wtS2, s2_bl, nullptr, hA, N, 256);

    // ---- readout ----
    gemm_mfma<256, 0, 128, 128, true, false, true><<<dim3(gx128, 1), 256, 0, stream>>>(
        hA, nullptr, wtR, ro_b1, f32buf, nullptr, N, 128);
    lin_final<<<(N * OUT_DIM + 255) / 256, 256, 0, stream>>>(f32buf, ro_w2, ro_b2, out, N);
}

// Round 13
// 229.907 us; speedup vs baseline: 1.4993x; 1.1286x over previous
//
#include <hip/hip_runtime.h>
#include <hip/hip_bf16.h>

#define N_NODES 50000
#define N_EDGES 400000
#define IN_DIM 24
#define HID 256
#define OUT_DIM 12

typedef _Float16 fp16_t;
typedef __attribute__((ext_vector_type(8))) _Float16 half8;
typedef __attribute__((ext_vector_type(4))) float f32x4;

// async global->LDS, 16 bytes per lane (dest must be linear: base + lane*16 per wave)
__device__ __forceinline__ void gload_lds16(const void* g, void* l) {
    typedef __attribute__((address_space(3))) unsigned int u32_lds;
    typedef const __attribute__((address_space(1))) unsigned int u32_glb;
    __builtin_amdgcn_global_load_lds((u32_glb*)(unsigned long long)g,
                                     (u32_lds*)(unsigned int)(unsigned long long)l,
                                     16, 0, 0);
}

// ---------------- encoder layer 1 (K=24, f32 compute, fp16 out) ----------------
template<int K, int M, int ROWS>
__global__ __launch_bounds__(M) void lin_enc1(const float* __restrict__ X,
                                              const float* __restrict__ W,
                                              const float* __restrict__ b,
                                              fp16_t* __restrict__ Y, int N) {
    __shared__ float xs[ROWS][K];
    const int row0 = blockIdx.x * ROWS;
    const int tid = threadIdx.x;
    for (int i = tid; i < ROWS * K; i += M) {
        int r = i / K, k = i - r * K;
        int gr = row0 + r;
        xs[r][k] = (gr < N) ? X[(long long)gr * K + k] : 0.f;
    }
    __syncthreads();
    const int j = tid;
    float acc[ROWS];
    float bj = b[j];
#pragma unroll
    for (int r = 0; r < ROWS; ++r) acc[r] = bj;
    for (int k = 0; k < K; ++k) {
        float w = W[k * M + j];
#pragma unroll
        for (int r = 0; r < ROWS; ++r) acc[r] = fmaf(xs[r][k], w, acc[r]);
    }
#pragma unroll
    for (int r = 0; r < ROWS; ++r) {
        int gr = row0 + r;
        if (gr < N) {
            float v = fmaxf(acc[r], 0.f);
            Y[(size_t)gr * M + j] = (fp16_t)v;
        }
    }
}

// ---- fused weight transpose to fp16 (all 4 weight sets) + deg zeroing ----
__global__ __launch_bounds__(256) void wtrans_all(
    const float* __restrict__ enc_w2,
    const float* __restrict__ s1_wl, const float* __restrict__ s1_wr,
    const float* __restrict__ s2_wl, const float* __restrict__ s2_wr,
    const float* __restrict__ ro_w1,
    fp16_t* __restrict__ wtE,
    fp16_t* __restrict__ wtS1,
    fp16_t* __restrict__ wtS2,
    fp16_t* __restrict__ wtR,
    int* __restrict__ deg, int N) {
    const int sE = 256 * 128, sS = 256 * 512, sR = 128 * 256;
    int idx = blockIdx.x * blockDim.x + threadIdx.x;
    if (idx < N) deg[idx] = 0;
    float v; fp16_t* p; int o;
    if (idx < sE) {
        int j = idx / 128, k = idx - j * 128;
        v = enc_w2[(size_t)k * 256 + j]; p = wtE; o = idx;
    } else if (idx < sE + sS) {
        int t = idx - sE; int j = t / 512, k = t - j * 512;
        v = (k < 256) ? s1_wl[(size_t)k * 256 + j] : s1_wr[(size_t)(k - 256) * 256 + j];
        p = wtS1; o = t;
    } else if (idx < sE + 2 * sS) {
        int t = idx - sE - sS; int j = t / 512, k = t - j * 512;
        v = (k < 256) ? s2_wl[(size_t)k * 256 + j] : s2_wr[(size_t)(k - 256) * 256 + j];
        p = wtS2; o = t;
    } else if (idx < sE + 2 * sS + sR) {
        int t = idx - sE - 2 * sS; int j = t / 256, k = t - j * 256;
        v = ro_w1[(size_t)k * 128 + j]; p = wtR; o = t;
    } else return;
    p[o] = (fp16_t)v;
}

// ---------------- MFMA fp16 GEMM (single weight plane) ----------------
// Block tile BM x BN, BK=32. Waves (BM/64)x(BN/64), wave tile 64x64 (4x4 frags 16x16x32).
// LDS 16B-chunk swizzle (verified R11/R12, conflicts=0): physical slot p of row holds
// logical chunk (p-(row>>1))&3 applied on the GLOBAL source; frag read slot=(lg+(row>>1))&3.
// MODE 0: A rows from A [N][K];  MODE 1: k<HID from A (mean), else A2 (h), both [N][HID]
template<int K, int MODE, int BM, int BN, bool WH16, bool RELU>
__global__ __launch_bounds__((BM / 64) * (BN / 64) * 64, 4) void gemm_mfma(
    const fp16_t* __restrict__ A, const fp16_t* __restrict__ A2,
    const fp16_t* __restrict__ W,
    const float* __restrict__ bias,
    fp16_t* __restrict__ Yh,
    int N, int M) {
    constexpr int NWR = BM / 64;
    constexpr int NWC = BN / 64;
    constexpr int NT = NWR * NWC * 64;
    __shared__ __align__(16) fp16_t ldsA[BM * 32];
    __shared__ __align__(16) fp16_t ldsB[BN * 32];
    const int tid = threadIdx.x;
    const int r0 = blockIdx.x * BM;
    const int j0 = blockIdx.y * BN;
    const int w = tid >> 6, lane = tid & 63;
    const int wr = w / NWC, wc = w % NWC;
    const int lrow = lane & 15, lg = lane >> 4;

    f32x4 acc[4][4] = {};

    for (int kc = 0; kc < K; kc += 32) {
        __syncthreads();
        const fp16_t* pa;
        int ka, KA;
        if (MODE == 1) {
            KA = HID;
            if (kc >= HID) { pa = A2; ka = kc - HID; }
            else           { pa = A;  ka = kc; }
        } else {
            KA = K; pa = A; ka = kc;
        }
#pragma unroll
        for (int c = tid; c < BM * 4; c += NT) {
            int row = c >> 2, p = c & 3;
            int g = (p - (row >> 1)) & 3;
            int gr = r0 + row; if (gr > N - 1) gr = N - 1;
            gload_lds16(pa + (size_t)gr * KA + ka + g * 8,
                        (char*)ldsA + (size_t)c * 16);
        }
#pragma unroll
        for (int c = tid; c < BN * 4; c += NT) {
            int row = c >> 2, p = c & 3;
            int g = (p - (row >> 1)) & 3;
            gload_lds16(W + (size_t)(j0 + row) * K + kc + g * 8,
                        (char*)ldsB + (size_t)c * 16);
        }
        __syncthreads();

        half8 a[4], b[4];
#pragma unroll
        for (int f = 0; f < 4; ++f) {
            int ar = wr * 64 + f * 16 + lrow;
            int sa = (lg + (ar >> 1)) & 3;
            a[f] = *(const half8*)&ldsA[ar * 32 + sa * 8];
            int br = wc * 64 + f * 16 + lrow;
            int sb = (lg + (br >> 1)) & 3;
            b[f] = *(const half8*)&ldsB[br * 32 + sb * 8];
        }
#pragma unroll
        for (int fi = 0; fi < 4; ++fi)
#pragma unroll
            for (int fj = 0; fj < 4; ++fj)
                acc[fi][fj] = __builtin_amdgcn_mfma_f32_16x16x32_f16(a[fi], b[fj], acc[fi][fj], 0, 0, 0);
    }

    // ---- epilogue: C/D layout col=lane&15, row=(lane>>4)*4+reg ----
#pragma unroll
    for (int fj = 0; fj < 4; ++fj) {
        int ocol = j0 + wc * 64 + fj * 16 + lrow;
        float bv = bias[ocol];
#pragma unroll
        for (int fi = 0; fi < 4; ++fi) {
#pragma unroll
            for (int r = 0; r < 4; ++r) {
                int orow = r0 + wr * 64 + fi * 16 + lg * 4 + r;
                if (orow < N) {
                    float v = acc[fi][fj][r] + bv;
                    if (RELU) v = fmaxf(v, 0.f);
                    if (WH16) Yh[(size_t)orow * M + ocol] = (fp16_t)v;
                }
            }
        }
    }
}

// ---------------- Fused readout: out = relu(A @ wtR^T + b1) @ W2 + b2 ----------------
// BM=128, BN=128 (full width), 256 thr = 4 waves (2x2). After the K-loop the block owns
// complete 128-wide rows; relu(acc+b1) goes to a swizzled LDS htile (16B-chunk XOR,
// phys=(q+(row>>1))&15), then waves 0-1 compute htile @ W2^T (fp16, cols padded to 16)
// with 4 MFMA each and write out[*, 0..11] directly.
__global__ __launch_bounds__(256, 3) void gemm_ro(
    const fp16_t* __restrict__ A,      // hA [N][256]
    const fp16_t* __restrict__ W,      // wtR [128][256]
    const float* __restrict__ b1,
    const float* __restrict__ W2,      // ro_w2 [128][12] f32
    const float* __restrict__ b2,
    float* __restrict__ out, int N) {
    constexpr int K = 256;
    __shared__ __align__(16) fp16_t ldsA[128 * 32];
    __shared__ __align__(16) fp16_t ldsB[128 * 32];
    __shared__ __align__(16) fp16_t htile[128 * 128];
    __shared__ __align__(16) fp16_t w2t[16 * 128];
    const int tid = threadIdx.x;
    const int r0 = blockIdx.x * 128;
    const int w = tid >> 6, lane = tid & 63;
    const int wr = w >> 1, wc = w & 1;
    const int lrow = lane & 15, lg = lane >> 4;

    // stage W2^T as fp16 [outcol 0..15][k 0..127], cols 12..15 zero
    for (int i = tid; i < 16 * 128; i += 256) {
        int c = i >> 7, k = i & 127;
        w2t[i] = (c < 12) ? (fp16_t)W2[k * 12 + c] : (fp16_t)0.f;
    }

    f32x4 acc[4][4] = {};
    for (int kc = 0; kc < K; kc += 32) {
        __syncthreads();
#pragma unroll
        for (int c = tid; c < 128 * 4; c += 256) {
            int row = c >> 2, p = c & 3;
            int g = (p - (row >> 1)) & 3;
            int gr = r0 + row; if (gr > N - 1) gr = N - 1;
            gload_lds16(A + (size_t)gr * K + kc + g * 8, (char*)ldsA + (size_t)c * 16);
        }
#pragma unroll
        for (int c = tid; c < 128 * 4; c += 256) {
            int row = c >> 2, p = c & 3;
            int g = (p - (row >> 1)) & 3;
            gload_lds16(W + (size_t)row * K + kc + g * 8, (char*)ldsB + (size_t)c * 16);
        }
        __syncthreads();

        half8 a[4], b[4];
#pragma unroll
        for (int f = 0; f < 4; ++f) {
            int ar = wr * 64 + f * 16 + lrow;
            int sa = (lg + (ar >> 1)) & 3;
            a[f] = *(const half8*)&ldsA[ar * 32 + sa * 8];
            int br = wc * 64 + f * 16 + lrow;
            int sb = (lg + (br >> 1)) & 3;
            b[f] = *(const half8*)&ldsB[br * 32 + sb * 8];
        }
#pragma unroll
        for (int fi = 0; fi < 4; ++fi)
#pragma unroll
            for (int fj = 0; fj < 4; ++fj)
                acc[fi][fj] = __builtin_amdgcn_mfma_f32_16x16x32_f16(a[fi], b[fj], acc[fi][fj], 0, 0, 0);
    }

    // epilogue 1: relu(acc + b1) -> htile (swizzled fp16)
#pragma unroll
    for (int fj = 0; fj < 4; ++fj) {
        int ocol = wc * 64 + fj * 16 + lrow;
        float bv = b1[ocol];
        int q = ocol >> 3;
#pragma unroll
        for (int fi = 0; fi < 4; ++fi) {
#pragma unroll
            for (int r = 0; r < 4; ++r) {
                int orow = wr * 64 + fi * 16 + lg * 4 + r;
                float v = fmaxf(acc[fi][fj][r] + bv, 0.f);
                int phys = (q + (orow >> 1)) & 15;
                htile[orow * 128 + phys * 8 + (ocol & 7)] = (fp16_t)v;
            }
        }
    }
    __syncthreads();

    // final: out(128x12) = htile(128x128) @ W2(128x12); waves 0-1 handle 64 rows each
    if (w < 2) {
        f32x4 accF[4] = {};
#pragma unroll
        for (int kt = 0; kt < 4; ++kt) {
            half8 bb = *(const half8*)&w2t[lrow * 128 + kt * 32 + lg * 8];
            half8 a[4];
#pragma unroll
            for (int f = 0; f < 4; ++f) {
                int ar = w * 64 + f * 16 + lrow;
                int q = kt * 4 + lg;
                int phys = (q + (ar >> 1)) & 15;
                a[f] = *(const half8*)&htile[ar * 128 + phys * 8];
            }
#pragma unroll
            for (int f = 0; f < 4; ++f)
                accF[f] = __builtin_amdgcn_mfma_f32_16x16x32_f16(a[f], bb, accF[f], 0, 0, 0);
        }
        if (lrow < OUT_DIM) {
            float bv = b2[lrow];
#pragma unroll
            for (int f = 0; f < 4; ++f) {
#pragma unroll
                for (int r = 0; r < 4; ++r) {
                    int orow = r0 + w * 64 + f * 16 + lg * 4 + r;
                    if (orow < N) out[(size_t)orow * OUT_DIM + lrow] = accF[f][r] + bv;
                }
            }
        }
    }
}

// ---------------- CSR build ----------------
__global__ void deg_kernel(const int* __restrict__ dst, int* __restrict__ deg, int E) {
    int e = blockIdx.x * blockDim.x + threadIdx.x;
    if (e < E) atomicAdd(&deg[dst[e]], 1);
}

// Stage 1: per-block inclusive scan (256 elems/block) + block total
__global__ __launch_bounds__(256) void scan_local(const int* __restrict__ deg,
                                                  int* __restrict__ locincl,
                                                  int* __restrict__ bsum, int N) {
    const int t = threadIdx.x;
    const int i = blockIdx.x * 256 + t;
    int v = (i < N) ? deg[i] : 0;
    const int lane = t & 63;
    int x = v;
#pragma unroll
    for (int off = 1; off < 64; off <<= 1) {
        int y = __shfl_up(x, off, 64);
        if (lane >= off) x += y;
    }
    __shared__ int wsum[4];
    if (lane == 63) wsum[t >> 6] = x;
    __syncthreads();
    const int wid = t >> 6;
    int add = 0;
    for (int wI = 0; wI < wid; ++wI) add += wsum[wI];
    x += add;
    if (i < N) locincl[i] = x;
    if (t == 255) bsum[blockIdx.x] = x;
}

// Stage 2: exclusive scan of block sums (B <= 256), single block
__global__ __launch_bounds__(256) void scan_bsum(int* __restrict__ bsum, int B) {
    const int t = threadIdx.x;
    int v = (t < B) ? bsum[t] : 0;
    const int lane = t & 63;
    int x = v;
#pragma unroll
    for (int off = 1; off < 64; off <<= 1) {
        int y = __shfl_up(x, off, 64);
        if (lane >= off) x += y;
    }
    __shared__ int wsum[4];
    if (lane == 63) wsum[t >> 6] = x;
    __syncthreads();
    const int wid = t >> 6;
    int add = 0;
    for (int wI = 0; wI < wid; ++wI) add += wsum[wI];
    x += add;
    if (t < B) bsum[t] = x - v;   // exclusive
}

// Stage 3: recombine -> exclusive rowptr + cursor
__global__ __launch_bounds__(256) void scan_final(const int* __restrict__ deg,
                                                  const int* __restrict__ locincl,
                                                  const int* __restrict__ bsum,
                                                  int* __restrict__ rowptr,
                                                  int* __restrict__ cursor, int N, int E) {
    const int i = blockIdx.x * 256 + threadIdx.x;
    if (i < N) {
        int excl = bsum[blockIdx.x] + locincl[i] - deg[i];
        rowptr[i] = excl;
        cursor[i] = excl;
    }
    if (i == 0) rowptr[N] = E;
}

__global__ void scatter_kernel(const int* __restrict__ src, const int* __restrict__ dst,
                               int* __restrict__ cursor, int* __restrict__ esrc, int E) {
    int e = blockIdx.x * blockDim.x + threadIdx.x;
    if (e < E) {
        int pos = atomicAdd(&cursor[dst[e]], 1);
        esrc[pos] = src[e];
    }
}

// ---------------- CSR mean-aggregation: wave-per-node, 16B/lane gathers ----------------
__global__ __launch_bounds__(256) void agg_csr(const fp16_t* __restrict__ h,
                                               const int* __restrict__ rowptr,
                                               const int* __restrict__ esrc,
                                               fp16_t* __restrict__ mean, int N) {
    const int n = blockIdx.x * 4 + (threadIdx.x >> 6);
    if (n >= N) return;
    const int lane = threadIdx.x & 63;
    const int half = lane >> 5;         // 0 or 1
    const int l32 = lane & 31;          // channel group 0..31 (8 ch each)
    const int r0 = rowptr[n];
    const int r1 = rowptr[n + 1];
    const int deg = r1 - r0;

    float acc[8];
#pragma unroll
    for (int j = 0; j < 8; ++j) acc[j] = 0.f;

    for (int e = r0 + half; e < r1; e += 2) {
        int s = esrc[e];
        half8 v = *(const half8*)&h[(size_t)s * HID + l32 * 8];
#pragma unroll
        for (int j = 0; j < 8; ++j) acc[j] += (float)v[j];
    }
#pragma unroll
    for (int j = 0; j < 8; ++j) acc[j] += __shfl(acc[j], lane ^ 32, 64);

    if (half == 0) {
        float inv = 1.0f / fmaxf((float)deg, 1.0f);
        half8 o;
#pragma unroll
        for (int j = 0; j < 8; ++j) o[j] = (fp16_t)(acc[j] * inv);
        *(half8*)&mean[(size_t)n * HID + l32 * 8] = o;
    }
}

extern "C" void kernel_launch(void* const* d_in, const int* in_sizes, int n_in,
                              void* d_out, int out_size, void* d_ws, size_t ws_size,
                              hipStream_t stream) {
    const float* x      = (const float*)d_in[0];
    const int*   eidx   = (const int*)d_in[1];
    const float* enc_w1 = (const float*)d_in[2];
    const float* enc_b1 = (const float*)d_in[3];
    const float* enc_w2 = (const float*)d_in[4];
    const float* enc_b2 = (const float*)d_in[5];
    const float* s1_wl  = (const float*)d_in[6];
    const float* s1_bl  = (const float*)d_in[7];
    const float* s1_wr  = (const float*)d_in[8];
    const float* s2_wl  = (const float*)d_in[9];
    const float* s2_bl  = (const float*)d_in[10];
    const float* s2_wr  = (const float*)d_in[11];
    const float* ro_w1  = (const float*)d_in[12];
    const float* ro_b1  = (const float*)d_in[13];
    const float* ro_w2  = (const float*)d_in[14];
    const float* ro_b2  = (const float*)d_in[15];
    float* out = (float*)d_out;

    const int N = N_NODES;
    const int E = N_EDGES;
    const int* src = eidx;
    const int* dst = eidx + E;

    char* ws = (char*)d_ws;
    size_t off = 0;
    auto alloc = [&](size_t bytes) { void* p = ws + off; off += (bytes + 255) & ~255ULL; return p; };
    int* deg     = (int*)alloc((size_t)N * 4);
    int* rowptr  = (int*)alloc((size_t)(N + 1) * 4);
    int* cursor  = (int*)alloc((size_t)N * 4);
    int* esrc    = (int*)alloc((size_t)E * 4);
    int* locincl = (int*)alloc((size_t)N * 4);
    int* bsum    = (int*)alloc((size_t)256 * 4);
    fp16_t* wtE  = (fp16_t*)alloc((size_t)256 * 128 * 2);
    fp16_t* wtS1 = (fp16_t*)alloc((size_t)256 * 512 * 2);
    fp16_t* wtS2 = (fp16_t*)alloc((size_t)256 * 512 * 2);
    fp16_t* wtR  = (fp16_t*)alloc((size_t)128 * 256 * 2);
    fp16_t* h0   = (fp16_t*)alloc((size_t)N * 128 * 2);
    fp16_t* hA   = (fp16_t*)alloc((size_t)N * HID * 2);
    fp16_t* hB   = (fp16_t*)alloc((size_t)N * HID * 2);
    fp16_t* mbuf = (fp16_t*)alloc((size_t)N * HID * 2);

    const int nb8 = (N + 7) / 8;
    const int gx128 = (N + 127) / 128;
    const int nbScan = (N + 255) / 256;
    const int nbAgg = (N + 3) / 4;
    const int wtTot = 256 * 128 + 2 * 256 * 512 + 128 * 256;

    // ---- weight transpose + deg zeroing (single fused launch, runs first) ----
    wtrans_all<<<(wtTot + 255) / 256, 256, 0, stream>>>(
        enc_w2, s1_wl, s1_wr, s2_wl, s2_wr, ro_w1, wtE, wtS1, wtS2, wtR, deg, N);

    // ---- CSR build ----
    deg_kernel<<<(E + 255) / 256, 256, 0, stream>>>(dst, deg, E);
    scan_local<<<nbScan, 256, 0, stream>>>(deg, locincl, bsum, N);
    scan_bsum<<<1, 256, 0, stream>>>(bsum, nbScan);
    scan_final<<<nbScan, 256, 0, stream>>>(deg, locincl, bsum, rowptr, cursor, N, E);
    scatter_kernel<<<(E + 255) / 256, 256, 0, stream>>>(src, dst, cursor, esrc, E);

    // ---- encoder ----
    lin_enc1<IN_DIM, 128, 8><<<nb8, 128, 0, stream>>>(x, enc_w1, enc_b1, h0, N);
    gemm_mfma<128, 0, 128, 256, true, true><<<dim3(gx128, 1), 512, 0, stream>>>(
        h0, nullptr, wtE, enc_b2, hA, N, 256);

    // ---- SAGE 1 ----
    agg_csr<<<nbAgg, 256, 0, stream>>>(hA, rowptr, esrc, mbuf, N);
    gemm_mfma<512, 1, 128, 256, true, true><<<dim3(gx128, 1), 512, 0, stream>>>(
        mbuf, hA, wtS1, s1_bl, hB, N, 256);

    // ---- SAGE 2 ----
    agg_csr<<<nbAgg, 256, 0, stream>>>(hB, rowptr, esrc, mbuf, N);
    gemm_mfma<512, 1, 128, 256, true, true><<<dim3(gx128, 1), 512, 0, stream>>>(
        mbuf, hB, wtS2, s2_bl, hA, N, 256);

    // ---- fused readout (ro1 GEMM + final projection in one kernel) ----
    gemm_ro<<<gx128, 256, 0, stream>>>(hA, wtR, ro_b1, ro_w2, ro_b2, out, N);
}